// Round 14
// baseline (354.544 us; speedup 1.0000x reference)
//
#include <hip/hip_runtime.h>

#define HH 512
#define WW 512
#define HWC (HH * WW)          // 262144 = 2^18
#define NV 50000
#define NB 4
#define NR (NB * NV)           // 200000 rows per branch
#define NQ (2 * NR)            // 400000 total queries
#define KVROWS (NR + 1)        // +1 dummy bias row per branch

typedef unsigned int uint32;

static __device__ __forceinline__ float4 ld4(const float* p) {
    return *reinterpret_cast<const float4*>(p);
}
// round-to-nearest-even f32 -> bf16 (as low 16 bits)
static __device__ __forceinline__ uint32 bf16rne(float x) {
    uint32 u = __float_as_uint(x);
    return (u + 0x7FFFu + ((u >> 16) & 1u)) >> 16;
}

// VOP3P packed f32 FMA. All operands are 64-bit pairs (round-13 lesson:
// a single 32-bit src0 is an invalid operand class). Weight pair w supplies
// the broadcast scalar: _lo broadcasts w.x, _hi broadcasts w.y.
static __device__ __forceinline__ void pk_fma_lo(float2& a, float2 w, float2 x) {
    asm("v_pk_fma_f32 %0, %1, %2, %0 op_sel:[0,0,0] op_sel_hi:[0,1,1]"
        : "+v"(a) : "v"(w), "v"(x));
}
static __device__ __forceinline__ void pk_fma_hi(float2& a, float2 w, float2 x) {
    asm("v_pk_fma_f32 %0, %1, %2, %0 op_sel:[1,0,0] op_sel_hi:[1,1,1]"
        : "+v"(a) : "v"(w), "v"(x));
}

// Sum across each 16-lane row via DPP (VALU pipe, no LDS).
static __device__ __forceinline__ float red16(float x) {
    float t;
    t = __int_as_float(__builtin_amdgcn_update_dpp(0, __float_as_int(x), 0xB1, 0xF, 0xF, true));  // quad_perm(1,0,3,2)
    x += t;
    t = __int_as_float(__builtin_amdgcn_update_dpp(0, __float_as_int(x), 0x4E, 0xF, 0xF, true));  // quad_perm(2,3,0,1)
    x += t;
    t = __int_as_float(__builtin_amdgcn_update_dpp(0, __float_as_int(x), 0x141, 0xF, 0xF, true)); // row_half_mirror
    x += t;
    t = __int_as_float(__builtin_amdgcn_update_dpp(0, __float_as_int(x), 0x140, 0xF, 0xF, true)); // row_mirror
    x += t;
    return x;
}

// ---------------------------------------------------------------------------
// K0: fast -1 fill of the grids buffer.
// ---------------------------------------------------------------------------
__global__ void k_fill(int4* __restrict__ p) {
    const int total = 2 * NB * HWC / 4;
    const int stride = gridDim.x * blockDim.x;
    const int4 v = make_int4(-1, -1, -1, -1);
    for (int i = blockIdx.x * blockDim.x + threadIdx.x; i < total; i += stride)
        p[i] = v;
}

// ---------------------------------------------------------------------------
// K1: scatter voxel indices into dense coord->index grids
// grids layout: [set(0=li,1=ra)][b][HWC], pre-filled with -1
// ---------------------------------------------------------------------------
__global__ void k_grid(const int* __restrict__ li_coors, const int* __restrict__ ra_coors,
                       int* __restrict__ grids) {
    int t = blockIdx.x * blockDim.x + threadIdx.x;
    if (t >= NQ) return;
    int set = t / NR;
    int r2 = t - set * NR;
    int b = r2 / NV;
    int n = r2 - b * NV;
    const int* co = (set == 0 ? li_coors : ra_coors) + (size_t)(b * NV + n) * 2;
    grids[(set * NB + b) * HWC + co[0] * WW + co[1]] = n;
}

// ---------------------------------------------------------------------------
// K2: K|V projection, wave-loop + 2-deep pipeline (round-10 structure).
// blockIdx.y = f (feats tensor). Output: packed KV[f^1] (K low16, V high16),
// plane layout [KVROWS][32] u32 — row NR is the DUMMY BIAS ROW (bk|bv).
// ---------------------------------------------------------------------------
__launch_bounds__(256)
__global__ void k_proj_kv(const float* __restrict__ li_feats, const float* __restrict__ ra_feats,
                          const float* __restrict__ w_qkv1, const float* __restrict__ b_qkv1,
                          const float* __restrict__ w_qkv2, const float* __restrict__ b_qkv2,
                          uint32* __restrict__ KV) {
    const int f = blockIdx.y;
    const float* feats = f ? ra_feats : li_feats;
    const float* wkv_g = f ? w_qkv1 : w_qkv2;   // weights of branch f^1
    const float* bkv_g = f ? b_qkv1 : b_qkv2;

    __shared__ float xs[4][2][64];
    const int wave = threadIdx.x >> 6;
    const int l    = threadIdx.x & 63;
    const int h    = l >> 5;         // which row of the pair
    const int j    = l & 31;         // output column

    const int gw = blockIdx.x * 4 + wave;          // global wave id
    const int gs = gridDim.x * 4;                  // wave stride

    int r0 = gw * 2;
    float xreg = feats[(size_t)r0 * 32 + l];       // prefetch pair 0 first

    float4 wk[8], wv[8];
#pragma unroll
    for (int i = 0; i < 8; ++i) {
        wk[i] = ld4(wkv_g + (32 + j) * 32 + i * 4);
        wv[i] = ld4(wkv_g + (64 + j) * 32 + i * 4);
    }
    const float bk = bkv_g[32 + j], bv = bkv_g[64 + j];

    uint32* KVb = KV + (size_t)(f ^ 1) * KVROWS * 32;

    if (blockIdx.x == 0 && threadIdx.x < 32)       // dummy bias row
        KVb[(size_t)NR * 32 + threadIdx.x] = bf16rne(bk) | (bf16rne(bv) << 16);

    int cur = 0;
    while (r0 < NR) {
        xs[wave][cur][l] = xreg;                   // stage current pair
        const int rn = r0 + gs * 2;
        if (rn < NR) xreg = feats[(size_t)rn * 32 + l];  // issue next load NOW

        const float* xp = &xs[wave][cur][h * 32];
        float ak = bk, av = bv;
#pragma unroll
        for (int i = 0; i < 8; ++i) {
            float4 x = *reinterpret_cast<const float4*>(xp + i * 4);  // broadcast
            ak += x.x * wk[i].x + x.y * wk[i].y + x.z * wk[i].z + x.w * wk[i].w;
            av += x.x * wv[i].x + x.y * wv[i].y + x.z * wv[i].z + x.w * wv[i].w;
        }
        KVb[(size_t)(r0 + h) * 32 + j] = bf16rne(ak) | (bf16rne(av) << 16);
        r0 = rn;
        cur ^= 1;
    }
}

// ---------------------------------------------------------------------------
// K3a: neighbor resolve. 1 thread per query; 9 independent grid loads.
// Writes [q][12]: BYTE offsets into the branch KV plane (bb*NV folded in;
// invalid/empty -> dummy row NR), plus 3 pad ints.
// ---------------------------------------------------------------------------
__global__ void k_nbr(const int* __restrict__ li_coors, const int* __restrict__ ra_coors,
                      const int* __restrict__ grids, int* __restrict__ nbr) {
    int q = blockIdx.x * 256 + threadIdx.x;
    if (q >= NQ) return;
    int br  = (q >= NR) ? 1 : 0;
    int rem = q - br * NR;
    int b   = rem / NV;
    const int* qc = br ? ra_coors : li_coors;
    const int* kvgrid = grids + ((br ^ 1) * NB + b) * HWC;
    const int2 rc = *reinterpret_cast<const int2*>(qc + (size_t)rem * 2);

    const int drs[9] = {0, -1, 1, 0, -1, 1, 0, -1, 1};
    const int dcs[9] = {0, 0, 0, 1, 1, 1, -1, -1, -1};
    const int base = b * NV;
    int v[9];
#pragma unroll
    for (int k = 0; k < 9; ++k) {
        int rr = rc.x + drs[k], cc = rc.y + dcs[k];
        bool valid = ((unsigned)rr < HH) & ((unsigned)cc < WW);
        int raw = kvgrid[valid ? rr * WW + cc : 0];
        int id = valid ? raw : -1;
        v[k] = (id >= 0 ? base + id : NR) * 128;   // byte offset; dummy row if miss
    }
    int4* np = reinterpret_cast<int4*>(nbr + (size_t)q * 12);
    np[0] = make_int4(v[0], v[1], v[2], v[3]);
    np[1] = make_int4(v[4], v[5], v[6], v[7]);
    np[2] = make_int4(v[8], 0, 0, 0);
}

// ---------------------------------------------------------------------------
// K3b: FUSED attention core: Q-proj + attention + out-proj + residual.
// 32 lanes per query, 4 queries per lane-group. Component-major LDS
// ([g][comp][4 queries]) so projections run as packed-FP32 v_pk_fma_f32
// (2 FMA/instr) over the query dimension; weight pairs broadcast via op_sel.
// ---------------------------------------------------------------------------
__launch_bounds__(256)
__global__ void k_attn(const int* __restrict__ nbr,
                       const float* __restrict__ li_feats, const float* __restrict__ ra_feats,
                       const float* __restrict__ w_qkv1, const float* __restrict__ b_qkv1,
                       const float* __restrict__ w_out1, const float* __restrict__ b_out1,
                       const float* __restrict__ w_qkv2, const float* __restrict__ b_qkv2,
                       const float* __restrict__ w_out2, const float* __restrict__ b_out2,
                       const uint32* __restrict__ KV, float* __restrict__ res) {
    __shared__ float xs[8][32][4];     // feats rows, component-major
    __shared__ float os[8][32][4];     // attention outputs, component-major
    const int g = threadIdx.x >> 5;
    const int j = threadIdx.x & 31;
    const int q0 = (blockIdx.x * 8 + g) * 4;   // 4 queries, never straddle b/br
    const int br  = (q0 >= NR) ? 1 : 0;
    const int rem = q0 - br * NR;
    const float* feats = br ? ra_feats : li_feats;
    const float* wqkv  = br ? w_qkv2 : w_qkv1;
    const float* bqkv  = br ? b_qkv2 : b_qkv1;
    const float* wout  = br ? w_out2 : w_out1;
    const float* bout  = br ? b_out2 : b_out1;
    const char* KVbr = (const char*)(KV + (size_t)br * KVROWS * 32);

    // ---- nbr metadata (uniform per group -> broadcast loads) ----------
    int4 a0[4], a1[4], a2[4];
#pragma unroll
    for (int u = 0; u < 4; ++u) {
        const int4* np = reinterpret_cast<const int4*>(nbr + (size_t)(q0 + u) * 12);
        a0[u] = np[0]; a1[u] = np[1]; a2[u] = np[2];
    }

    // ---- feats rows: Q input + residual, staged component-major -------
    float4 frv;
    frv.x = feats[(size_t)(rem + 0) * 32 + j];
    frv.y = feats[(size_t)(rem + 1) * 32 + j];
    frv.z = feats[(size_t)(rem + 2) * 32 + j];
    frv.w = feats[(size_t)(rem + 3) * 32 + j];
    *reinterpret_cast<float4*>(xs[g][j]) = frv;    // one ds_write_b128

    // ---- 36 KV gathers issued now; Q-proj below hides their latency --
    const int joff = j * 4;
    uint32 kvw[4][9];
#pragma unroll
    for (int u = 0; u < 4; ++u) {
        int off[9] = {a0[u].x, a0[u].y, a0[u].z, a0[u].w,
                      a1[u].x, a1[u].y, a1[u].z, a1[u].w, a2[u].x};
#pragma unroll
        for (int k = 0; k < 9; ++k)
            kvw[u][k] = *reinterpret_cast<const uint32*>(KVbr + (size_t)(unsigned)(off[k] + joff));
    }

    // ---- Q projection, packed f32 over queries ------------------------
    const float bq = bqkv[j];
    float2 q01 = make_float2(bq, bq), q23 = make_float2(bq, bq);
#pragma unroll
    for (int i = 0; i < 8; ++i) {
        float4 w = ld4(wqkv + j * 32 + i * 4);
        float2 w01 = make_float2(w.x, w.y);
        float2 w23 = make_float2(w.z, w.w);
        float4 x0 = *reinterpret_cast<const float4*>(xs[g][i * 4 + 0]);
        float4 x1 = *reinterpret_cast<const float4*>(xs[g][i * 4 + 1]);
        float4 x2 = *reinterpret_cast<const float4*>(xs[g][i * 4 + 2]);
        float4 x3 = *reinterpret_cast<const float4*>(xs[g][i * 4 + 3]);
        pk_fma_lo(q01, w01, make_float2(x0.x, x0.y));
        pk_fma_lo(q23, w01, make_float2(x0.z, x0.w));
        pk_fma_hi(q01, w01, make_float2(x1.x, x1.y));
        pk_fma_hi(q23, w01, make_float2(x1.z, x1.w));
        pk_fma_lo(q01, w23, make_float2(x2.x, x2.y));
        pk_fma_lo(q23, w23, make_float2(x2.z, x2.w));
        pk_fma_hi(q01, w23, make_float2(x3.x, x3.y));
        pk_fma_hi(q23, w23, make_float2(x3.z, x3.w));
    }
    const float SC = 0.25f * 1.44269504f;   // 1/sqrt(16) * log2(e)
    float Qf[4] = {q01.x * SC, q01.y * SC, q23.x * SC, q23.y * SC};

    // ---- scores + softmax (no max-sub, base-2) + weighted V -----------
    float4 ov;
#pragma unroll
    for (int u = 0; u < 4; ++u) {
        float sum = 0.f, o = 0.f;
#pragma unroll
        for (int k = 0; k < 9; ++k) {
            float kk = __uint_as_float(kvw[u][k] << 16);
            float e = exp2f(red16(Qf[u] * kk));
            float vv = __uint_as_float(kvw[u][k] & 0xFFFF0000u);
            sum += e;
            o += e * vv;
        }
        float r = o / sum;
        if (u == 0) ov.x = r; else if (u == 1) ov.y = r;
        else if (u == 2) ov.z = r; else ov.w = r;
    }
    *reinterpret_cast<float4*>(os[g][j]) = ov;     // one ds_write_b128

    // ---- out-projection (packed f32) + residual ------------------------
    const float bo = bout[j];
    float2 o01 = make_float2(bo, bo), o23 = make_float2(bo, bo);
#pragma unroll
    for (int i = 0; i < 8; ++i) {
        float4 w = ld4(wout + j * 32 + i * 4);
        float2 w01 = make_float2(w.x, w.y);
        float2 w23 = make_float2(w.z, w.w);
        float4 x0 = *reinterpret_cast<const float4*>(os[g][i * 4 + 0]);
        float4 x1 = *reinterpret_cast<const float4*>(os[g][i * 4 + 1]);
        float4 x2 = *reinterpret_cast<const float4*>(os[g][i * 4 + 2]);
        float4 x3 = *reinterpret_cast<const float4*>(os[g][i * 4 + 3]);
        pk_fma_lo(o01, w01, make_float2(x0.x, x0.y));
        pk_fma_lo(o23, w01, make_float2(x0.z, x0.w));
        pk_fma_hi(o01, w01, make_float2(x1.x, x1.y));
        pk_fma_hi(o23, w01, make_float2(x1.z, x1.w));
        pk_fma_lo(o01, w23, make_float2(x2.x, x2.y));
        pk_fma_lo(o23, w23, make_float2(x2.z, x2.w));
        pk_fma_hi(o01, w23, make_float2(x3.x, x3.y));
        pk_fma_hi(o23, w23, make_float2(x3.z, x3.w));
    }
    res[(size_t)(q0 + 0) * 32 + j] = frv.x + o01.x;
    res[(size_t)(q0 + 1) * 32 + j] = frv.y + o01.y;
    res[(size_t)(q0 + 2) * 32 + j] = frv.z + o23.x;
    res[(size_t)(q0 + 3) * 32 + j] = frv.w + o23.y;
}

// ---------------------------------------------------------------------------
// K4: densify (inverted scatter). One thread per output cell; writes all 32
// channel planes coalesced with NON-TEMPORAL stores (out is never re-read;
// keeps the 256MB stream from evicting res, which this kernel gathers).
// ---------------------------------------------------------------------------
__launch_bounds__(256)
__global__ void k_densify(const int* __restrict__ grids, const float* __restrict__ res,
                          float* __restrict__ out) {
    int t = blockIdx.x * 256 + threadIdx.x;  // 0 .. 2*NB*HWC-1
    int plane = t >> 18;                     // (br*NB + b)
    int s = t & (HWC - 1);
    int gidx = grids[t];                     // query grid (set==branch)
    float4 v[8];
    if (gidx >= 0) {
        const float* rp = res + ((size_t)plane * NV + gidx) * 32;
#pragma unroll
        for (int i = 0; i < 8; ++i) v[i] = ld4(rp + i * 4);
    } else {
#pragma unroll
        for (int i = 0; i < 8; ++i) v[i] = make_float4(0.f, 0.f, 0.f, 0.f);
    }
    float* ob = out + (size_t)plane * 32 * HWC + s;
#pragma unroll
    for (int i = 0; i < 8; ++i) {
        __builtin_nontemporal_store(v[i].x, ob + (size_t)(4 * i + 0) * HWC);
        __builtin_nontemporal_store(v[i].y, ob + (size_t)(4 * i + 1) * HWC);
        __builtin_nontemporal_store(v[i].z, ob + (size_t)(4 * i + 2) * HWC);
        __builtin_nontemporal_store(v[i].w, ob + (size_t)(4 * i + 3) * HWC);
    }
}

// ---------------------------------------------------------------------------
extern "C" void kernel_launch(void* const* d_in, const int* in_sizes, int n_in,
                              void* d_out, int out_size, void* d_ws, size_t ws_size,
                              hipStream_t stream) {
    const float* li_feats = (const float*)d_in[0];
    const int*   li_coors = (const int*)d_in[1];
    const float* ra_feats = (const float*)d_in[2];
    const int*   ra_coors = (const int*)d_in[3];
    const float* w_qkv1 = (const float*)d_in[4];
    const float* b_qkv1 = (const float*)d_in[5];
    const float* w_out1 = (const float*)d_in[6];
    const float* b_out1 = (const float*)d_in[7];
    const float* w_qkv2 = (const float*)d_in[8];
    const float* b_qkv2 = (const float*)d_in[9];
    const float* w_out2 = (const float*)d_in[10];
    const float* b_out2 = (const float*)d_in[11];
    float* out = (float*)d_out;

    char* ws = (char*)d_ws;
    size_t off = 0;
    int*    grids = (int*)(ws + off);    off += (size_t)2 * NB * HWC * 4;    // 8 MB
    uint32* KV    = (uint32*)(ws + off); off += (size_t)2 * KVROWS * 32 * 4; // 51.2 MB (+2 dummy rows)
    float*  res   = (float*)(ws + off);  off += (size_t)NQ * 32 * 4;         // 51.2 MB fp32
    int*    nbr   = (int*)(ws + off);    off += (size_t)NQ * 12 * 4;         // 19.2 MB

    k_fill<<<2048, 256, 0, stream>>>((int4*)grids);

    k_grid<<<(NQ + 255) / 256, 256, 0, stream>>>(li_coors, ra_coors, grids);

    k_proj_kv<<<dim3(3200, 2), 256, 0, stream>>>(
        li_feats, ra_feats, w_qkv1, b_qkv1, w_qkv2, b_qkv2, KV);

    k_nbr<<<(NQ + 255) / 256, 256, 0, stream>>>(li_coors, ra_coors, grids, nbr);

    k_attn<<<NQ / 32, 256, 0, stream>>>(
        nbr, li_feats, ra_feats,
        w_qkv1, b_qkv1, w_out1, b_out1,
        w_qkv2, b_qkv2, w_out2, b_out2,
        KV, res);

    k_densify<<<(2 * NB * HWC) / 256, 256, 0, stream>>>(grids, res, out);
}

// Round 15
// 272.203 us; speedup vs baseline: 1.3025x; 1.3025x over previous
//
#include <hip/hip_runtime.h>

#define HH 512
#define WW 512
#define HWC (HH * WW)          // 262144 = 2^18
#define NV 50000
#define NB 4
#define NR (NB * NV)           // 200000 rows per branch
#define NQ (2 * NR)            // 400000 total queries
#define KVROWS (NR + 1)        // +1 dummy bias row per branch

typedef unsigned int uint32;

static __device__ __forceinline__ float4 ld4(const float* p) {
    return *reinterpret_cast<const float4*>(p);
}
// round-to-nearest-even f32 -> bf16 (as low 16 bits)
static __device__ __forceinline__ uint32 bf16rne(float x) {
    uint32 u = __float_as_uint(x);
    return (u + 0x7FFFu + ((u >> 16) & 1u)) >> 16;
}

// Sum across each 16-lane row via DPP (VALU pipe, no LDS).
static __device__ __forceinline__ float red16(float x) {
    float t;
    t = __int_as_float(__builtin_amdgcn_update_dpp(0, __float_as_int(x), 0xB1, 0xF, 0xF, true));  // quad_perm(1,0,3,2)
    x += t;
    t = __int_as_float(__builtin_amdgcn_update_dpp(0, __float_as_int(x), 0x4E, 0xF, 0xF, true));  // quad_perm(2,3,0,1)
    x += t;
    t = __int_as_float(__builtin_amdgcn_update_dpp(0, __float_as_int(x), 0x141, 0xF, 0xF, true)); // row_half_mirror
    x += t;
    t = __int_as_float(__builtin_amdgcn_update_dpp(0, __float_as_int(x), 0x140, 0xF, 0xF, true)); // row_mirror
    x += t;
    return x;
}

// ---------------------------------------------------------------------------
// K0: fast -1 fill of the grids buffer.
// ---------------------------------------------------------------------------
__global__ void k_fill(int4* __restrict__ p) {
    const int total = 2 * NB * HWC / 4;
    const int stride = gridDim.x * blockDim.x;
    const int4 v = make_int4(-1, -1, -1, -1);
    for (int i = blockIdx.x * blockDim.x + threadIdx.x; i < total; i += stride)
        p[i] = v;
}

// ---------------------------------------------------------------------------
// K1: scatter voxel indices into dense coord->index grids
// grids layout: [set(0=li,1=ra)][b][HWC], pre-filled with -1
// ---------------------------------------------------------------------------
__global__ void k_grid(const int* __restrict__ li_coors, const int* __restrict__ ra_coors,
                       int* __restrict__ grids) {
    int t = blockIdx.x * blockDim.x + threadIdx.x;
    if (t >= NQ) return;
    int set = t / NR;
    int r2 = t - set * NR;
    int b = r2 / NV;
    int n = r2 - b * NV;
    const int* co = (set == 0 ? li_coors : ra_coors) + (size_t)(b * NV + n) * 2;
    grids[(set * NB + b) * HWC + co[0] * WW + co[1]] = n;
}

// ---------------------------------------------------------------------------
// K2: K|V projection, wave-loop + 2-deep pipeline (round-10 structure).
// blockIdx.y = f (feats tensor). Output: packed KV[f^1] (K low16, V high16),
// plane layout [KVROWS][32] u32 — row NR is the DUMMY BIAS ROW (bk|bv).
// ---------------------------------------------------------------------------
__launch_bounds__(256)
__global__ void k_proj_kv(const float* __restrict__ li_feats, const float* __restrict__ ra_feats,
                          const float* __restrict__ w_qkv1, const float* __restrict__ b_qkv1,
                          const float* __restrict__ w_qkv2, const float* __restrict__ b_qkv2,
                          uint32* __restrict__ KV) {
    const int f = blockIdx.y;
    const float* feats = f ? ra_feats : li_feats;
    const float* wkv_g = f ? w_qkv1 : w_qkv2;   // weights of branch f^1
    const float* bkv_g = f ? b_qkv1 : b_qkv2;

    __shared__ float xs[4][2][64];
    const int wave = threadIdx.x >> 6;
    const int l    = threadIdx.x & 63;
    const int h    = l >> 5;         // which row of the pair
    const int j    = l & 31;         // output column

    const int gw = blockIdx.x * 4 + wave;          // global wave id
    const int gs = gridDim.x * 4;                  // wave stride

    int r0 = gw * 2;
    float xreg = feats[(size_t)r0 * 32 + l];       // prefetch pair 0 first

    float4 wk[8], wv[8];
#pragma unroll
    for (int i = 0; i < 8; ++i) {
        wk[i] = ld4(wkv_g + (32 + j) * 32 + i * 4);
        wv[i] = ld4(wkv_g + (64 + j) * 32 + i * 4);
    }
    const float bk = bkv_g[32 + j], bv = bkv_g[64 + j];

    uint32* KVb = KV + (size_t)(f ^ 1) * KVROWS * 32;

    if (blockIdx.x == 0 && threadIdx.x < 32)       // dummy bias row
        KVb[(size_t)NR * 32 + threadIdx.x] = bf16rne(bk) | (bf16rne(bv) << 16);

    int cur = 0;
    while (r0 < NR) {
        xs[wave][cur][l] = xreg;                   // stage current pair
        const int rn = r0 + gs * 2;
        if (rn < NR) xreg = feats[(size_t)rn * 32 + l];  // issue next load NOW

        const float* xp = &xs[wave][cur][h * 32];
        float ak = bk, av = bv;
#pragma unroll
        for (int i = 0; i < 8; ++i) {
            float4 x = *reinterpret_cast<const float4*>(xp + i * 4);  // broadcast
            ak += x.x * wk[i].x + x.y * wk[i].y + x.z * wk[i].z + x.w * wk[i].w;
            av += x.x * wv[i].x + x.y * wv[i].y + x.z * wv[i].z + x.w * wv[i].w;
        }
        KVb[(size_t)(r0 + h) * 32 + j] = bf16rne(ak) | (bf16rne(av) << 16);
        r0 = rn;
        cur ^= 1;
    }
}

// ---------------------------------------------------------------------------
// K3a: neighbor resolve. 1 thread per query; 9 independent grid loads.
// Writes [q][12]: BYTE offsets into the branch KV plane (bb*NV folded in;
// invalid/empty -> dummy row NR), plus 3 pad ints.
// ---------------------------------------------------------------------------
__global__ void k_nbr(const int* __restrict__ li_coors, const int* __restrict__ ra_coors,
                      const int* __restrict__ grids, int* __restrict__ nbr) {
    int q = blockIdx.x * 256 + threadIdx.x;
    if (q >= NQ) return;
    int br  = (q >= NR) ? 1 : 0;
    int rem = q - br * NR;
    int b   = rem / NV;
    const int* qc = br ? ra_coors : li_coors;
    const int* kvgrid = grids + ((br ^ 1) * NB + b) * HWC;
    const int2 rc = *reinterpret_cast<const int2*>(qc + (size_t)rem * 2);

    const int drs[9] = {0, -1, 1, 0, -1, 1, 0, -1, 1};
    const int dcs[9] = {0, 0, 0, 1, 1, 1, -1, -1, -1};
    const int base = b * NV;
    int v[9];
#pragma unroll
    for (int k = 0; k < 9; ++k) {
        int rr = rc.x + drs[k], cc = rc.y + dcs[k];
        bool valid = ((unsigned)rr < HH) & ((unsigned)cc < WW);
        int raw = kvgrid[valid ? rr * WW + cc : 0];
        int id = valid ? raw : -1;
        v[k] = (id >= 0 ? base + id : NR) * 128;   // byte offset; dummy row if miss
    }
    int4* np = reinterpret_cast<int4*>(nbr + (size_t)q * 12);
    np[0] = make_int4(v[0], v[1], v[2], v[3]);
    np[1] = make_int4(v[4], v[5], v[6], v[7]);
    np[2] = make_int4(v[8], 0, 0, 0);
}

// ---------------------------------------------------------------------------
// K3b: FUSED attention core: Q-proj + attention + out-proj + residual.
// 32 lanes per query, 4 queries per lane-group. Round-12 scalar-FMA form
// (round-14 pk_fma asm regressed: 2 packed chains halve ILP and the opaque
// asm blocks compiler scheduling — VALUBusy 69%->37%, dur +60%). VALU diet:
//   - dummy bias row -> no valid-mask selects
//   - no max-subtraction (scores bounded ~|4|, exp2 overflow at 128)
//   - 0.25*log2(e) folded into Q once; exp2f == v_exp_f32 directly
//   - gathers: 32-bit byte-offset + lane j*4, single add each
// ---------------------------------------------------------------------------
__launch_bounds__(256)
__global__ void k_attn(const int* __restrict__ nbr,
                       const float* __restrict__ li_feats, const float* __restrict__ ra_feats,
                       const float* __restrict__ w_qkv1, const float* __restrict__ b_qkv1,
                       const float* __restrict__ w_out1, const float* __restrict__ b_out1,
                       const float* __restrict__ w_qkv2, const float* __restrict__ b_qkv2,
                       const float* __restrict__ w_out2, const float* __restrict__ b_out2,
                       const uint32* __restrict__ KV, float* __restrict__ res) {
    __shared__ float xs[8][4][32];     // feats rows
    __shared__ float os[8][4][32];     // attention outputs
    const int g = threadIdx.x >> 5;
    const int j = threadIdx.x & 31;
    const int q0 = (blockIdx.x * 8 + g) * 4;   // 4 queries, never straddle b/br
    const int br  = (q0 >= NR) ? 1 : 0;
    const int rem = q0 - br * NR;
    const float* feats = br ? ra_feats : li_feats;
    const float* wqkv  = br ? w_qkv2 : w_qkv1;
    const float* bqkv  = br ? b_qkv2 : b_qkv1;
    const float* wout  = br ? w_out2 : w_out1;
    const float* bout  = br ? b_out2 : b_out1;
    const char* KVbr = (const char*)(KV + (size_t)br * KVROWS * 32);

    // ---- nbr metadata (uniform per group -> broadcast loads) ----------
    int4 a0[4], a1[4], a2[4];
#pragma unroll
    for (int u = 0; u < 4; ++u) {
        const int4* np = reinterpret_cast<const int4*>(nbr + (size_t)(q0 + u) * 12);
        a0[u] = np[0]; a1[u] = np[1]; a2[u] = np[2];
    }

    // ---- feats rows: Q input + residual, staged to LDS ---------------
    float fr[4];
#pragma unroll
    for (int u = 0; u < 4; ++u) {
        fr[u] = feats[(size_t)(rem + u) * 32 + j];
        xs[g][u][j] = fr[u];
    }

    // ---- 36 KV gathers issued now; Q-proj below hides their latency --
    const int joff = j * 4;
    uint32 kvw[4][9];
#pragma unroll
    for (int u = 0; u < 4; ++u) {
        int off[9] = {a0[u].x, a0[u].y, a0[u].z, a0[u].w,
                      a1[u].x, a1[u].y, a1[u].z, a1[u].w, a2[u].x};
#pragma unroll
        for (int k = 0; k < 9; ++k)
            kvw[u][k] = *reinterpret_cast<const uint32*>(KVbr + (size_t)(unsigned)(off[k] + joff));
    }

    // ---- Q projection (wq regs die after this block) ------------------
    const float bq = bqkv[j];
    float Qf[4] = {bq, bq, bq, bq};
#pragma unroll
    for (int i = 0; i < 8; ++i) {
        float4 w = ld4(wqkv + j * 32 + i * 4);
#pragma unroll
        for (int u = 0; u < 4; ++u) {
            float4 x = *reinterpret_cast<const float4*>(&xs[g][u][i * 4]);
            Qf[u] += x.x * w.x + x.y * w.y + x.z * w.z + x.w * w.w;
        }
    }
    const float SC = 0.25f * 1.44269504f;   // 1/sqrt(16) * log2(e)
#pragma unroll
    for (int u = 0; u < 4; ++u) Qf[u] *= SC;

    // ---- scores + softmax (no max-sub, base-2) + weighted V -----------
#pragma unroll
    for (int u = 0; u < 4; ++u) {
        float sum = 0.f, o = 0.f;
#pragma unroll
        for (int k = 0; k < 9; ++k) {
            float kk = __uint_as_float(kvw[u][k] << 16);
            float e = exp2f(red16(Qf[u] * kk));
            float vv = __uint_as_float(kvw[u][k] & 0xFFFF0000u);
            sum += e;
            o += e * vv;
        }
        os[g][u][j] = o / sum;   // intra-wave producer/consumer: no barrier
    }

    // ---- out-projection + residual ------------------------------------
    const float bo = bout[j];
    float outv[4] = {bo, bo, bo, bo};
#pragma unroll
    for (int i = 0; i < 8; ++i) {
        float4 w = ld4(wout + j * 32 + i * 4);
#pragma unroll
        for (int u = 0; u < 4; ++u) {
            float4 x = *reinterpret_cast<const float4*>(&os[g][u][i * 4]);
            outv[u] += x.x * w.x + x.y * w.y + x.z * w.z + x.w * w.w;
        }
    }
#pragma unroll
    for (int u = 0; u < 4; ++u)
        res[(size_t)(q0 + u) * 32 + j] = fr[u] + outv[u];
}

// ---------------------------------------------------------------------------
// K4: densify (inverted scatter). One thread per output cell; writes all 32
// channel planes coalesced with NON-TEMPORAL stores (out is never re-read;
// keeps the 256MB stream from evicting res, which this kernel gathers).
// Round-14 attribution: NT stores worth ~-20us — kept.
// ---------------------------------------------------------------------------
__launch_bounds__(256)
__global__ void k_densify(const int* __restrict__ grids, const float* __restrict__ res,
                          float* __restrict__ out) {
    int t = blockIdx.x * 256 + threadIdx.x;  // 0 .. 2*NB*HWC-1
    int plane = t >> 18;                     // (br*NB + b)
    int s = t & (HWC - 1);
    int gidx = grids[t];                     // query grid (set==branch)
    float4 v[8];
    if (gidx >= 0) {
        const float* rp = res + ((size_t)plane * NV + gidx) * 32;
#pragma unroll
        for (int i = 0; i < 8; ++i) v[i] = ld4(rp + i * 4);
    } else {
#pragma unroll
        for (int i = 0; i < 8; ++i) v[i] = make_float4(0.f, 0.f, 0.f, 0.f);
    }
    float* ob = out + (size_t)plane * 32 * HWC + s;
#pragma unroll
    for (int i = 0; i < 8; ++i) {
        __builtin_nontemporal_store(v[i].x, ob + (size_t)(4 * i + 0) * HWC);
        __builtin_nontemporal_store(v[i].y, ob + (size_t)(4 * i + 1) * HWC);
        __builtin_nontemporal_store(v[i].z, ob + (size_t)(4 * i + 2) * HWC);
        __builtin_nontemporal_store(v[i].w, ob + (size_t)(4 * i + 3) * HWC);
    }
}

// ---------------------------------------------------------------------------
extern "C" void kernel_launch(void* const* d_in, const int* in_sizes, int n_in,
                              void* d_out, int out_size, void* d_ws, size_t ws_size,
                              hipStream_t stream) {
    const float* li_feats = (const float*)d_in[0];
    const int*   li_coors = (const int*)d_in[1];
    const float* ra_feats = (const float*)d_in[2];
    const int*   ra_coors = (const int*)d_in[3];
    const float* w_qkv1 = (const float*)d_in[4];
    const float* b_qkv1 = (const float*)d_in[5];
    const float* w_out1 = (const float*)d_in[6];
    const float* b_out1 = (const float*)d_in[7];
    const float* w_qkv2 = (const float*)d_in[8];
    const float* b_qkv2 = (const float*)d_in[9];
    const float* w_out2 = (const float*)d_in[10];
    const float* b_out2 = (const float*)d_in[11];
    float* out = (float*)d_out;

    char* ws = (char*)d_ws;
    size_t off = 0;
    int*    grids = (int*)(ws + off);    off += (size_t)2 * NB * HWC * 4;    // 8 MB
    uint32* KV    = (uint32*)(ws + off); off += (size_t)2 * KVROWS * 32 * 4; // 51.2 MB (+2 dummy rows)
    float*  res   = (float*)(ws + off);  off += (size_t)NQ * 32 * 4;         // 51.2 MB fp32
    int*    nbr   = (int*)(ws + off);    off += (size_t)NQ * 12 * 4;         // 19.2 MB

    k_fill<<<2048, 256, 0, stream>>>((int4*)grids);

    k_grid<<<(NQ + 255) / 256, 256, 0, stream>>>(li_coors, ra_coors, grids);

    k_proj_kv<<<dim3(3200, 2), 256, 0, stream>>>(
        li_feats, ra_feats, w_qkv1, b_qkv1, w_qkv2, b_qkv2, KV);

    k_nbr<<<(NQ + 255) / 256, 256, 0, stream>>>(li_coors, ra_coors, grids, nbr);

    k_attn<<<NQ / 32, 256, 0, stream>>>(
        nbr, li_feats, ra_feats,
        w_qkv1, b_qkv1, w_out1, b_out1,
        w_qkv2, b_qkv2, w_out2, b_out2,
        KV, res);

    k_densify<<<(2 * NB * HWC) / 256, 256, 0, stream>>>(grids, res, out);
}

// Round 17
// 258.031 us; speedup vs baseline: 1.3740x; 1.0549x over previous
//
#include <hip/hip_runtime.h>

#define HH 512
#define WW 512
#define HWC (HH * WW)          // 262144 = 2^18
#define NV 50000
#define NB 4
#define NR (NB * NV)           // 200000 rows per branch
#define NQ (2 * NR)            // 400000 total queries
#define KVROWS (NR + 1)        // +1 dummy bias row per branch

typedef unsigned int uint32;

static __device__ __forceinline__ float4 ld4(const float* p) {
    return *reinterpret_cast<const float4*>(p);
}
// round-to-nearest-even f32 -> bf16 (as low 16 bits)
static __device__ __forceinline__ uint32 bf16rne(float x) {
    uint32 u = __float_as_uint(x);
    return (u + 0x7FFFu + ((u >> 16) & 1u)) >> 16;
}
// DPP ctrl must be an integer-constant expression (round-16 lesson) -> template.
template <int CTRL>
static __device__ __forceinline__ float dpp_add(float x) {
    float t = __int_as_float(__builtin_amdgcn_update_dpp(0, __float_as_int(x), CTRL, 0xF, 0xF, true));
    return x + t;
}

// ---------------------------------------------------------------------------
// K0: fast -1 fill of the grids buffer.
// ---------------------------------------------------------------------------
__global__ void k_fill(int4* __restrict__ p) {
    const int total = 2 * NB * HWC / 4;
    const int stride = gridDim.x * blockDim.x;
    const int4 v = make_int4(-1, -1, -1, -1);
    for (int i = blockIdx.x * blockDim.x + threadIdx.x; i < total; i += stride)
        p[i] = v;
}

// ---------------------------------------------------------------------------
// K1: scatter voxel indices into dense coord->index grids
// grids layout: [set(0=li,1=ra)][b][HWC], pre-filled with -1
// ---------------------------------------------------------------------------
__global__ void k_grid(const int* __restrict__ li_coors, const int* __restrict__ ra_coors,
                       int* __restrict__ grids) {
    int t = blockIdx.x * blockDim.x + threadIdx.x;
    if (t >= NQ) return;
    int set = t / NR;
    int r2 = t - set * NR;
    int b = r2 / NV;
    int n = r2 - b * NV;
    const int* co = (set == 0 ? li_coors : ra_coors) + (size_t)(b * NV + n) * 2;
    grids[(set * NB + b) * HWC + co[0] * WW + co[1]] = n;
}

// ---------------------------------------------------------------------------
// K2: K|V projection, wave-loop + 2-deep pipeline (round-10 structure).
// blockIdx.y = f (feats tensor). Output: packed KV[f^1] (K low16, V high16),
// plane layout [KVROWS][32] u32 — row NR is the DUMMY BIAS ROW (bk|bv).
// ---------------------------------------------------------------------------
__launch_bounds__(256)
__global__ void k_proj_kv(const float* __restrict__ li_feats, const float* __restrict__ ra_feats,
                          const float* __restrict__ w_qkv1, const float* __restrict__ b_qkv1,
                          const float* __restrict__ w_qkv2, const float* __restrict__ b_qkv2,
                          uint32* __restrict__ KV) {
    const int f = blockIdx.y;
    const float* feats = f ? ra_feats : li_feats;
    const float* wkv_g = f ? w_qkv1 : w_qkv2;   // weights of branch f^1
    const float* bkv_g = f ? b_qkv1 : b_qkv2;

    __shared__ float xs[4][2][64];
    const int wave = threadIdx.x >> 6;
    const int l    = threadIdx.x & 63;
    const int h    = l >> 5;         // which row of the pair
    const int j    = l & 31;         // output column

    const int gw = blockIdx.x * 4 + wave;          // global wave id
    const int gs = gridDim.x * 4;                  // wave stride

    int r0 = gw * 2;
    float xreg = feats[(size_t)r0 * 32 + l];       // prefetch pair 0 first

    float4 wk[8], wv[8];
#pragma unroll
    for (int i = 0; i < 8; ++i) {
        wk[i] = ld4(wkv_g + (32 + j) * 32 + i * 4);
        wv[i] = ld4(wkv_g + (64 + j) * 32 + i * 4);
    }
    const float bk = bkv_g[32 + j], bv = bkv_g[64 + j];

    uint32* KVb = KV + (size_t)(f ^ 1) * KVROWS * 32;

    if (blockIdx.x == 0 && threadIdx.x < 32)       // dummy bias row
        KVb[(size_t)NR * 32 + threadIdx.x] = bf16rne(bk) | (bf16rne(bv) << 16);

    int cur = 0;
    while (r0 < NR) {
        xs[wave][cur][l] = xreg;                   // stage current pair
        const int rn = r0 + gs * 2;
        if (rn < NR) xreg = feats[(size_t)rn * 32 + l];  // issue next load NOW

        const float* xp = &xs[wave][cur][h * 32];
        float ak = bk, av = bv;
#pragma unroll
        for (int i = 0; i < 8; ++i) {
            float4 x = *reinterpret_cast<const float4*>(xp + i * 4);  // broadcast
            ak += x.x * wk[i].x + x.y * wk[i].y + x.z * wk[i].z + x.w * wk[i].w;
            av += x.x * wv[i].x + x.y * wv[i].y + x.z * wv[i].z + x.w * wv[i].w;
        }
        KVb[(size_t)(r0 + h) * 32 + j] = bf16rne(ak) | (bf16rne(av) << 16);
        r0 = rn;
        cur ^= 1;
    }
}

// ---------------------------------------------------------------------------
// K3a: neighbor resolve. 1 thread per query; 9 independent grid loads.
// Writes [q][12]: BYTE offsets into the branch KV plane (bb*NV folded in;
// invalid/empty -> dummy row NR), plus 3 pad ints.
// ---------------------------------------------------------------------------
__global__ void k_nbr(const int* __restrict__ li_coors, const int* __restrict__ ra_coors,
                      const int* __restrict__ grids, int* __restrict__ nbr) {
    int q = blockIdx.x * 256 + threadIdx.x;
    if (q >= NQ) return;
    int br  = (q >= NR) ? 1 : 0;
    int rem = q - br * NR;
    int b   = rem / NV;
    const int* qc = br ? ra_coors : li_coors;
    const int* kvgrid = grids + ((br ^ 1) * NB + b) * HWC;
    const int2 rc = *reinterpret_cast<const int2*>(qc + (size_t)rem * 2);

    const int drs[9] = {0, -1, 1, 0, -1, 1, 0, -1, 1};
    const int dcs[9] = {0, 0, 0, 1, 1, 1, -1, -1, -1};
    const int base = b * NV;
    int v[9];
#pragma unroll
    for (int k = 0; k < 9; ++k) {
        int rr = rc.x + drs[k], cc = rc.y + dcs[k];
        bool valid = ((unsigned)rr < HH) & ((unsigned)cc < WW);
        int raw = kvgrid[valid ? rr * WW + cc : 0];
        int id = valid ? raw : -1;
        v[k] = (id >= 0 ? base + id : NR) * 128;   // byte offset; dummy row if miss
    }
    int4* np = reinterpret_cast<int4*>(nbr + (size_t)q * 12);
    np[0] = make_int4(v[0], v[1], v[2], v[3]);
    np[1] = make_int4(v[4], v[5], v[6], v[7]);
    np[2] = make_int4(v[8], 0, 0, 0);
}

// ---------------------------------------------------------------------------
// K3b: FUSED attention core, three-stage lane remap:
//   A (32 lanes/query, 4 q/group): Q-proj with wq rows in VGPRs.
//   B (8 lanes/query, 4 channels/lane): scores via in-lane dot4 + 2-step
//     quad_perm DPP reduce (quads == heads), exp2, PV accumulate.
//     Cuts the score stage from ~504 to ~198 wave-instrs per 8 queries;
//     gathers 36 dword -> 9 dwordx4 issues.
//   C (32 lanes/query): out-proj + residual.
// Q and o move between mappings via padded LDS (intra-wave, no barriers).
// Gathers issue before Q-proj so projection math hides their latency.
// ---------------------------------------------------------------------------
__launch_bounds__(256)
__global__ void k_attn(const int* __restrict__ nbr,
                       const float* __restrict__ li_feats, const float* __restrict__ ra_feats,
                       const float* __restrict__ w_qkv1, const float* __restrict__ b_qkv1,
                       const float* __restrict__ w_out1, const float* __restrict__ b_out1,
                       const float* __restrict__ w_qkv2, const float* __restrict__ b_qkv2,
                       const float* __restrict__ w_out2, const float* __restrict__ b_out2,
                       const uint32* __restrict__ KV, float* __restrict__ res) {
    __shared__ float xs[8][4][32];     // feats rows (A mapping)
    __shared__ float Qls[4][8][36];    // scaled Q, padded rows
    __shared__ float os[4][8][36];     // attention outputs, padded rows
    const int tid = threadIdx.x;
    const int w = tid >> 6;            // wave in block
    const int l = tid & 63;            // lane in wave
    const int g = tid >> 5;            // 32-lane group (A/C mapping)
    const int j = tid & 31;
    const int wq0 = (blockIdx.x * 4 + w) * 8;    // wave's first query
    const int br  = (wq0 >= NR) ? 1 : 0;
    const float* feats = br ? ra_feats : li_feats;
    const float* wqkv  = br ? w_qkv2 : w_qkv1;
    const float* bqkv  = br ? b_qkv2 : b_qkv1;
    const float* wout  = br ? w_out2 : w_out1;
    const float* bout  = br ? b_out2 : b_out1;
    const char* KVbr = (const char*)(KV + (size_t)br * KVROWS * 32);

    // ---- B mapping: nbr offsets + all 9 dwordx4 gathers issued first ---
    const int qB = wq0 + (l >> 3);                // this lane's B query
    const int4* np = reinterpret_cast<const int4*>(nbr + (size_t)qB * 12);
    int4 b0 = np[0], b1 = np[1], b2 = np[2];
    const int coff = (l & 7) * 16;                // channel-byte offset
    int off[9] = {b0.x, b0.y, b0.z, b0.w, b1.x, b1.y, b1.z, b1.w, b2.x};
    uint4 kv4[9];
#pragma unroll
    for (int k = 0; k < 9; ++k)
        kv4[k] = *reinterpret_cast<const uint4*>(KVbr + (size_t)(unsigned)(off[k] + coff));

    // ---- Stage A: feats rows + Q projection (32 lanes/query) ----------
    const int qrow = (l >> 5) << 2;               // 0 or 4: wave-local query base
    const int remA = wq0 + qrow - br * NR;
    float fr[4];
#pragma unroll
    for (int u = 0; u < 4; ++u) {
        fr[u] = feats[(size_t)(remA + u) * 32 + j];
        xs[g][u][j] = fr[u];
    }
    const float bq = bqkv[j];
    float Qf[4] = {bq, bq, bq, bq};
#pragma unroll
    for (int i = 0; i < 8; ++i) {
        float4 wv4 = ld4(wqkv + j * 32 + i * 4);
#pragma unroll
        for (int u = 0; u < 4; ++u) {
            float4 x = *reinterpret_cast<const float4*>(&xs[g][u][i * 4]);
            Qf[u] += x.x * wv4.x + x.y * wv4.y + x.z * wv4.z + x.w * wv4.w;
        }
    }
    const float SC = 0.25f * 1.44269504f;   // 1/sqrt(16) * log2(e)
#pragma unroll
    for (int u = 0; u < 4; ++u) Qls[w][qrow + u][j] = Qf[u] * SC;

    // ---- Stage B: scores + softmax + PV (8 lanes/query) ---------------
    float4 q4 = *reinterpret_cast<const float4*>(&Qls[w][l >> 3][(l & 7) * 4]);
    float o0 = 0.f, o1 = 0.f, o2 = 0.f, o3 = 0.f, sum = 0.f;
#pragma unroll
    for (int k = 0; k < 9; ++k) {
        uint4 c = kv4[k];
        float k0 = __uint_as_float(c.x << 16);
        float k1 = __uint_as_float(c.y << 16);
        float k2 = __uint_as_float(c.z << 16);
        float k3 = __uint_as_float(c.w << 16);
        float d = q4.x * k0 + q4.y * k1 + q4.z * k2 + q4.w * k3;
        d = dpp_add<0xB1>(d);                     // quad_perm(1,0,3,2)
        d = dpp_add<0x4E>(d);                     // quad_perm(2,3,0,1) -> quad sum
        float e = exp2f(d);                       // quads == heads: per-head score
        sum += e;
        o0 += e * __uint_as_float(c.x & 0xFFFF0000u);
        o1 += e * __uint_as_float(c.y & 0xFFFF0000u);
        o2 += e * __uint_as_float(c.z & 0xFFFF0000u);
        o3 += e * __uint_as_float(c.w & 0xFFFF0000u);
    }
    const float rs = 1.0f / sum;                  // per-head denominator
    *reinterpret_cast<float4*>(&os[w][l >> 3][(l & 7) * 4]) =
        make_float4(o0 * rs, o1 * rs, o2 * rs, o3 * rs);

    // ---- Stage C: out-projection + residual (32 lanes/query) ----------
    const float bo = bout[j];
    float outv[4] = {bo, bo, bo, bo};
#pragma unroll
    for (int i = 0; i < 8; ++i) {
        float4 wv4 = ld4(wout + j * 32 + i * 4);
#pragma unroll
        for (int u = 0; u < 4; ++u) {
            float4 x = *reinterpret_cast<const float4*>(&os[w][qrow + u][i * 4]);  // broadcast
            outv[u] += x.x * wv4.x + x.y * wv4.y + x.z * wv4.z + x.w * wv4.w;
        }
    }
#pragma unroll
    for (int u = 0; u < 4; ++u)
        res[(size_t)(wq0 + qrow + u) * 32 + j] = fr[u] + outv[u];
}

// ---------------------------------------------------------------------------
// K4: densify (inverted scatter). One thread per output cell; writes all 32
// channel planes coalesced with NON-TEMPORAL stores (out is never re-read;
// keeps the 256MB stream from evicting res, which this kernel gathers).
// ---------------------------------------------------------------------------
__launch_bounds__(256)
__global__ void k_densify(const int* __restrict__ grids, const float* __restrict__ res,
                          float* __restrict__ out) {
    int t = blockIdx.x * 256 + threadIdx.x;  // 0 .. 2*NB*HWC-1
    int plane = t >> 18;                     // (br*NB + b)
    int s = t & (HWC - 1);
    int gidx = grids[t];                     // query grid (set==branch)
    float4 v[8];
    if (gidx >= 0) {
        const float* rp = res + ((size_t)plane * NV + gidx) * 32;
#pragma unroll
        for (int i = 0; i < 8; ++i) v[i] = ld4(rp + i * 4);
    } else {
#pragma unroll
        for (int i = 0; i < 8; ++i) v[i] = make_float4(0.f, 0.f, 0.f, 0.f);
    }
    float* ob = out + (size_t)plane * 32 * HWC + s;
#pragma unroll
    for (int i = 0; i < 8; ++i) {
        __builtin_nontemporal_store(v[i].x, ob + (size_t)(4 * i + 0) * HWC);
        __builtin_nontemporal_store(v[i].y, ob + (size_t)(4 * i + 1) * HWC);
        __builtin_nontemporal_store(v[i].z, ob + (size_t)(4 * i + 2) * HWC);
        __builtin_nontemporal_store(v[i].w, ob + (size_t)(4 * i + 3) * HWC);
    }
}

// ---------------------------------------------------------------------------
extern "C" void kernel_launch(void* const* d_in, const int* in_sizes, int n_in,
                              void* d_out, int out_size, void* d_ws, size_t ws_size,
                              hipStream_t stream) {
    const float* li_feats = (const float*)d_in[0];
    const int*   li_coors = (const int*)d_in[1];
    const float* ra_feats = (const float*)d_in[2];
    const int*   ra_coors = (const int*)d_in[3];
    const float* w_qkv1 = (const float*)d_in[4];
    const float* b_qkv1 = (const float*)d_in[5];
    const float* w_out1 = (const float*)d_in[6];
    const float* b_out1 = (const float*)d_in[7];
    const float* w_qkv2 = (const float*)d_in[8];
    const float* b_qkv2 = (const float*)d_in[9];
    const float* w_out2 = (const float*)d_in[10];
    const float* b_out2 = (const float*)d_in[11];
    float* out = (float*)d_out;

    char* ws = (char*)d_ws;
    size_t off = 0;
    int*    grids = (int*)(ws + off);    off += (size_t)2 * NB * HWC * 4;    // 8 MB
    uint32* KV    = (uint32*)(ws + off); off += (size_t)2 * KVROWS * 32 * 4; // 51.2 MB (+2 dummy rows)
    float*  res   = (float*)(ws + off);  off += (size_t)NQ * 32 * 4;         // 51.2 MB fp32
    int*    nbr   = (int*)(ws + off);    off += (size_t)NQ * 12 * 4;         // 19.2 MB

    k_fill<<<2048, 256, 0, stream>>>((int4*)grids);

    k_grid<<<(NQ + 255) / 256, 256, 0, stream>>>(li_coors, ra_coors, grids);

    k_proj_kv<<<dim3(3200, 2), 256, 0, stream>>>(
        li_feats, ra_feats, w_qkv1, b_qkv1, w_qkv2, b_qkv2, KV);

    k_nbr<<<(NQ + 255) / 256, 256, 0, stream>>>(li_coors, ra_coors, grids, nbr);

    k_attn<<<NQ / 32, 256, 0, stream>>>(
        nbr, li_feats, ra_feats,
        w_qkv1, b_qkv1, w_out1, b_out1,
        w_qkv2, b_qkv2, w_out2, b_out2,
        KV, res);

    k_densify<<<(2 * NB * HWC) / 256, 256, 0, stream>>>(grids, res, out);
}